// Round 7
// baseline (308.589 us; speedup 1.0000x reference)
//
#include <hip/hip_runtime.h>
#include <hip/hip_bf16.h>

#define BS 32
#define NBC 33

typedef unsigned long long ull;
typedef __attribute__((ext_vector_type(8))) __bf16 bf16x8;
typedef __attribute__((ext_vector_type(4))) float f32x4;
typedef __attribute__((ext_vector_type(4))) unsigned short us4;

__device__ __forceinline__ unsigned short f2b(float f) {
    __hip_bfloat16 h = __float2bfloat16(f);
    return *reinterpret_cast<unsigned short*>(&h);
}
__device__ __forceinline__ float b2f(unsigned short u) {
    union { unsigned int i; float f; } x; x.i = ((unsigned int)u) << 16; return x.f;
}
#define LD8(p) (*reinterpret_cast<const bf16x8*>(p))

// ---- fused: zero the ull table (blocks 0..ZB-1) + repack weights (blocks ZB..) ----
#define ZB 2048
__global__ void zero_prepack_kernel(uint4* __restrict__ tbl4, int n4,
                                    const float* __restrict__ qkv_w,
                                    const float* __restrict__ proj_w,
                                    unsigned short* __restrict__ wq,
                                    unsigned short* __restrict__ wp) {
    if (blockIdx.x < ZB) {
        int stride = ZB * 256;
        for (int i = blockIdx.x * 256 + threadIdx.x; i < n4; i += stride)
            tbl4[i] = make_uint4(0u, 0u, 0u, 0u);
    } else {
        int tid = (blockIdx.x - ZB) * 256 + threadIdx.x;   // 0..65535
        int f = tid >> 9, lane = (tid >> 3) & 63, j = tid & 7;
        int ks = f & 3;
        int kk = ks * 32 + (lane >> 4) * 8 + j;
        int nn = lane & 15;
        if (f < 96) {
            int t = f >> 2;                 // 0..23
            int w = t / 6, s = t % 6;
            int g = (s < 2) ? (2 * w + s) : (s < 4) ? (8 + 2 * w + (s - 2)) : (16 + 2 * w + (s - 4));
            wq[tid] = f2b(qkv_w[kk * 384 + g * 16 + nn]);
        } else {
            int f2 = f - 96;                // proj frag = nt_global*4+ks
            wp[f2 * 512 + lane * 8 + j] = f2b(proj_w[kk * 128 + (f2 >> 2) * 16 + nn]);
        }
    }
}

// ---- pass 1: last-edge-wins scatter; key = (edge_id+1)<<32 | float_bits(value) ----
__global__ void edge_scatter_kernel(const int* __restrict__ rows,
                                    const int* __restrict__ cols,
                                    const float* __restrict__ vals,
                                    ull* __restrict__ tbl, int E) {
    int base = (blockIdx.x * 256 + threadIdx.x) * 4;
    if (base >= E) return;
    if (base + 4 <= E) {
        int4 r4 = *reinterpret_cast<const int4*>(rows + base);
        int4 c4 = *reinterpret_cast<const int4*>(cols + base);
        float4 v4 = *reinterpret_cast<const float4*>(vals + base);
        int rr[4] = {r4.x, r4.y, r4.z, r4.w};
        int cc[4] = {c4.x, c4.y, c4.z, c4.w};
        float vv[4] = {v4.x, v4.y, v4.z, v4.w};
        #pragma unroll
        for (int k = 0; k < 4; ++k) {
            int r = rr[k], c = cc[k];
            if ((r >> 5) == (c >> 5) && r != c) {
                ull key = ((ull)(unsigned)(base + k + 1) << 32) | (ull)__float_as_uint(vv[k]);
                atomicMax(&tbl[((size_t)(r >> 5) * BS + (r & 31)) * NBC + (c & 31)], key);
            }
        }
    } else {
        for (int e = base; e < E && e < base + 4; ++e) {
            int r = rows[e], c = cols[e];
            if ((r >> 5) == (c >> 5) && r != c) {
                ull key = ((ull)(unsigned)(e + 1) << 32) | (ull)__float_as_uint(vals[e]);
                atomicMax(&tbl[((size_t)(r >> 5) * BS + (r & 31)) * NBC + (c & 31)], key);
            }
        }
    }
}

// ---- main fused kernel: one 4-wave WG per block; wave w owns head w end-to-end ----
// __launch_bounds__(256,5): 5 waves/SIMD target -> VGPR budget ~102 (no spills);
// LDS 31040 B -> 5 WGs/CU.
__global__ __launch_bounds__(256, 5)
void block_attn_kernel(const float* __restrict__ x,
                       const ull* __restrict__ tbl,
                       const unsigned short* __restrict__ wq,
                       const unsigned short* __restrict__ wp,
                       const float* __restrict__ qkv_b,
                       const float* __restrict__ proj_b,
                       const float* __restrict__ gate_w,
                       const float* __restrict__ gate_b,
                       float* __restrict__ out) {
    __shared__ __align__(16) unsigned char smem[31040];
    unsigned short (*qs)[32][40]  = (unsigned short (*)[32][40])(smem);           // 10240 B: Q -> P -> attn-out
    unsigned short (*ksm)[33][40] = (unsigned short (*)[33][40])(smem + 10240);   // 10560 B: K rows 0-31 + mean(32)
    unsigned short (*vT)[32][40]  = (unsigned short (*)[32][40])(smem + 20800);   // 10240 B: V^T; col32=mean, col33=pcol
    unsigned short (*xs)[136]     = (unsigned short (*)[136])(smem + 20800);      //  8704 B overlay (x staging)

    const int b = blockIdx.x, t = threadIdx.x;
    const int w = t >> 6, l = t & 63, g16 = l >> 4, c16 = l & 15;
    const f32x4 z4 = {0.f, 0.f, 0.f, 0.f};
    const float NEG = -1.0e30f;

    // ---- phase 0: stage x block (coalesced float4 -> bf16 LDS) ----
    const float* xb = x + (size_t)b * (BS * 128);
    #pragma unroll
    for (int it = 0; it < 4; ++it) {
        int idx = (t + it * 256) * 4;
        float4 v = *reinterpret_cast<const float4*>(xb + idx);
        us4 u; u.x = f2b(v.x); u.y = f2b(v.y); u.z = f2b(v.z); u.w = f2b(v.w);
        *reinterpret_cast<us4*>(&xs[idx >> 7][idx & 127]) = u;
    }

    // ---- edge bias wb per score slot from packed table (value embedded) ----
    float wb[2][4][3];
    {
        const ull* tb = tbl + (size_t)b * (BS * NBC);
        #pragma unroll
        for (int mt = 0; mt < 2; ++mt)
            #pragma unroll
            for (int r = 0; r < 4; ++r) {
                const int i = 16 * mt + 4 * g16 + r;
                #pragma unroll
                for (int nt = 0; nt < 2; ++nt) {
                    const int j = 16 * nt + c16;
                    const ull wv = tb[i * NBC + j];
                    wb[mt][r][nt] = (j == i) ? 1.f
                                   : (wv ? __uint_as_float((unsigned)(wv & 0xffffffffu)) : NEG);
                }
                wb[mt][r][2] = (c16 == 0) ? 1.f : NEG;
            }
    }
    __syncthreads();   // x staged

    // ---- A-fragments from LDS ----
    bf16x8 a[2][4];
    #pragma unroll
    for (int mt = 0; mt < 2; ++mt)
        #pragma unroll
        for (int ks = 0; ks < 4; ++ks)
            a[mt][ks] = LD8(&xs[c16 + 16 * mt][ks * 32 + g16 * 8]);
    __syncthreads();   // xs consumed; overlay region may now be written as vT

    // ---- QKV for head w: 6 n-tiles (q0,q1,k0,k1,v0,v1), K=128, bn double-buffer ----
    {
        const unsigned short* wqs = wq + (size_t)(w * 24) * 512 + l * 8;
        bf16x8 bn[4];
        #pragma unroll
        for (int ks = 0; ks < 4; ++ks) bn[ks] = LD8(wqs + ks * 512);
        #pragma unroll
        for (int s = 0; s < 6; ++s) {
            bf16x8 bc[4];
            #pragma unroll
            for (int ks = 0; ks < 4; ++ks) bc[ks] = bn[ks];
            if (s < 5) {
                #pragma unroll
                for (int ks = 0; ks < 4; ++ks) bn[ks] = LD8(wqs + ((s + 1) * 4 + ks) * 512);
            }
            f32x4 acc0 = z4, acc1 = z4;
            __builtin_amdgcn_s_setprio(1);
            #pragma unroll
            for (int ks = 0; ks < 4; ++ks) {
                acc0 = __builtin_amdgcn_mfma_f32_16x16x32_bf16(a[0][ks], bc[ks], acc0, 0, 0, 0);
                acc1 = __builtin_amdgcn_mfma_f32_16x16x32_bf16(a[1][ks], bc[ks], acc1, 0, 0, 0);
            }
            __builtin_amdgcn_s_setprio(0);
            const float bias = qkv_b[(s >> 1) * 128 + 32 * w + 16 * (s & 1) + c16];
            const int cc = 16 * (s & 1) + c16;
            if (s < 2) {
                #pragma unroll
                for (int r = 0; r < 4; ++r) {
                    qs[w][4 * g16 + r][cc]      = f2b(acc0[r] + bias);
                    qs[w][16 + 4 * g16 + r][cc] = f2b(acc1[r] + bias);
                }
            } else {
                float csum = acc0[0] + acc0[1] + acc0[2] + acc0[3]
                           + acc1[0] + acc1[1] + acc1[2] + acc1[3];
                csum += __shfl_xor(csum, 16, 64);
                csum += __shfl_xor(csum, 32, 64);
                const float meanv = csum * (1.f / 32.f) + bias;
                if (s < 4) {
                    #pragma unroll
                    for (int r = 0; r < 4; ++r) {
                        ksm[w][4 * g16 + r][cc]      = f2b(acc0[r] + bias);
                        ksm[w][16 + 4 * g16 + r][cc] = f2b(acc1[r] + bias);
                    }
                    if (g16 == 0) ksm[w][32][cc] = f2b(meanv);
                } else {
                    #pragma unroll
                    for (int r = 0; r < 4; ++r) {
                        vT[w][cc][4 * g16 + r]      = f2b(acc0[r] + bias);
                        vT[w][cc][16 + 4 * g16 + r] = f2b(acc1[r] + bias);
                    }
                    if (g16 == 0) vT[w][cc][32] = f2b(meanv);
                }
            }
        }
    }
    __syncthreads();   // drain QKV staging

    // ---- QK^T (K=32); mean-row fragment masked to lanes c16==0 via select ----
    f32x4 s[2][3];
    {
        bf16x8 aq0 = LD8(&qs[w][c16][g16 * 8]);
        bf16x8 aq1 = LD8(&qs[w][16 + c16][g16 * 8]);
        bf16x8 bk0 = LD8(&ksm[w][c16][g16 * 8]);
        bf16x8 bk1 = LD8(&ksm[w][16 + c16][g16 * 8]);
        bf16x8 bk2 = LD8(&ksm[w][32][g16 * 8]);      // mean row, broadcast
        bf16x8 zb;
        #pragma unroll
        for (int q = 0; q < 8; ++q) zb[q] = (__bf16)0.f;
        if (c16 != 0) bk2 = zb;                       // cols 33-47 of tile 2 -> zero
        __builtin_amdgcn_s_setprio(1);
        s[0][0] = __builtin_amdgcn_mfma_f32_16x16x32_bf16(aq0, bk0, z4, 0, 0, 0);
        s[0][1] = __builtin_amdgcn_mfma_f32_16x16x32_bf16(aq0, bk1, z4, 0, 0, 0);
        s[0][2] = __builtin_amdgcn_mfma_f32_16x16x32_bf16(aq0, bk2, z4, 0, 0, 0);
        s[1][0] = __builtin_amdgcn_mfma_f32_16x16x32_bf16(aq1, bk0, z4, 0, 0, 0);
        s[1][1] = __builtin_amdgcn_mfma_f32_16x16x32_bf16(aq1, bk1, z4, 0, 0, 0);
        s[1][2] = __builtin_amdgcn_mfma_f32_16x16x32_bf16(aq1, bk2, z4, 0, 0, 0);
        __builtin_amdgcn_s_setprio(0);
    }

    // ---- softmax with max-subtraction + gate; stage P (combined) ----
    {
        const float scale = 0.17677669529663687f;   // 32^-0.5
        const float gwh = gate_w[w], gbh = gate_b[w];
        #pragma unroll
        for (int mt = 0; mt < 2; ++mt)
            #pragma unroll
            for (int r = 0; r < 4; ++r) {
                const int i = 16 * mt + 4 * g16 + r;
                float sc[3];
                #pragma unroll
                for (int k = 0; k < 3; ++k) sc[k] = s[mt][k][r] * scale + wb[mt][r][k];
                float mx = fmaxf(fmaxf(sc[0], sc[1]), sc[2]);
                mx = fmaxf(mx, __shfl_xor(mx, 1, 64));
                mx = fmaxf(mx, __shfl_xor(mx, 2, 64));
                mx = fmaxf(mx, __shfl_xor(mx, 4, 64));
                mx = fmaxf(mx, __shfl_xor(mx, 8, 64));
                float e0 = __expf(sc[0] - mx), e1 = __expf(sc[1] - mx), e2 = __expf(sc[2] - mx);
                float sum = e0 + e1 + e2;
                sum += __shfl_xor(sum, 1, 64);
                sum += __shfl_xor(sum, 2, 64);
                sum += __shfl_xor(sum, 4, 64);
                sum += __shfl_xor(sum, 8, 64);
                const float inv = __builtin_amdgcn_rcpf(sum);
                float gt0 = (wb[mt][r][0] > -1.0e29f) ? wb[mt][r][0] * gwh + gbh : 0.f;
                float gt1 = (wb[mt][r][1] > -1.0e29f) ? wb[mt][r][1] * gwh + gbh : 0.f;
                float gt2 = (wb[mt][r][2] > -1.0e29f) ? gwh + gbh : 0.f;
                qs[w][i][c16]      = f2b(e0 * inv + gt0);
                qs[w][i][16 + c16] = f2b(e1 * inv + gt1);
                if (c16 == 0) vT[w][i][33] = f2b(e2 * inv + gt2);   // pcol
            }
    }
    __syncthreads();   // drain P staging

    // ---- PV (rows 0-31 via MFMA, block-node row via rank-1) -> attn-out into qs ----
    {
        bf16x8 ap0 = LD8(&qs[w][c16][g16 * 8]);
        bf16x8 ap1 = LD8(&qs[w][16 + c16][g16 * 8]);
        f32x4 o[2][2];
        __builtin_amdgcn_s_setprio(1);
        #pragma unroll
        for (int nt = 0; nt < 2; ++nt) {
            bf16x8 bv = LD8(&vT[w][16 * nt + c16][g16 * 8]);
            o[0][nt] = __builtin_amdgcn_mfma_f32_16x16x32_bf16(ap0, bv, z4, 0, 0, 0);
            o[1][nt] = __builtin_amdgcn_mfma_f32_16x16x32_bf16(ap1, bv, z4, 0, 0, 0);
        }
        __builtin_amdgcn_s_setprio(0);
        #pragma unroll
        for (int nt = 0; nt < 2; ++nt) {
            const float vm = b2f(vT[w][16 * nt + c16][32]);
            #pragma unroll
            for (int mt = 0; mt < 2; ++mt)
                #pragma unroll
                for (int r = 0; r < 4; ++r)
                    o[mt][nt][r] += b2f(vT[w][16 * mt + 4 * g16 + r][33]) * vm;
        }
        #pragma unroll
        for (int mt = 0; mt < 2; ++mt)
            #pragma unroll
            for (int nt = 0; nt < 2; ++nt)
                #pragma unroll
                for (int r = 0; r < 4; ++r)
                    qs[w][16 * mt + 4 * g16 + r][16 * nt + c16] = f2b(o[mt][nt][r]);
    }
    __syncthreads();   // all heads' attn-out ready

    // ---- projection: k-step h reads head-h buffer; wave w owns out cols [32w,32w+32) ----
    {
        bf16x8 aa[2][4];
        #pragma unroll
        for (int mt = 0; mt < 2; ++mt)
            #pragma unroll
            for (int h = 0; h < 4; ++h)
                aa[mt][h] = LD8(&qs[h][c16 + 16 * mt][g16 * 8]);
        f32x4 po[2][2];
        po[0][0] = z4; po[0][1] = z4; po[1][0] = z4; po[1][1] = z4;
        const unsigned short* wps = wp + l * 8;
        #pragma unroll
        for (int nt = 0; nt < 2; ++nt) {
            bf16x8 bw0 = LD8(wps + (size_t)((2 * w + nt) * 4 + 0) * 512);
            bf16x8 bw1 = LD8(wps + (size_t)((2 * w + nt) * 4 + 1) * 512);
            bf16x8 bw2 = LD8(wps + (size_t)((2 * w + nt) * 4 + 2) * 512);
            bf16x8 bw3 = LD8(wps + (size_t)((2 * w + nt) * 4 + 3) * 512);
            __builtin_amdgcn_s_setprio(1);
            po[0][nt] = __builtin_amdgcn_mfma_f32_16x16x32_bf16(aa[0][0], bw0, po[0][nt], 0, 0, 0);
            po[1][nt] = __builtin_amdgcn_mfma_f32_16x16x32_bf16(aa[1][0], bw0, po[1][nt], 0, 0, 0);
            po[0][nt] = __builtin_amdgcn_mfma_f32_16x16x32_bf16(aa[0][1], bw1, po[0][nt], 0, 0, 0);
            po[1][nt] = __builtin_amdgcn_mfma_f32_16x16x32_bf16(aa[1][1], bw1, po[1][nt], 0, 0, 0);
            po[0][nt] = __builtin_amdgcn_mfma_f32_16x16x32_bf16(aa[0][2], bw2, po[0][nt], 0, 0, 0);
            po[1][nt] = __builtin_amdgcn_mfma_f32_16x16x32_bf16(aa[1][2], bw2, po[1][nt], 0, 0, 0);
            po[0][nt] = __builtin_amdgcn_mfma_f32_16x16x32_bf16(aa[0][3], bw3, po[0][nt], 0, 0, 0);
            po[1][nt] = __builtin_amdgcn_mfma_f32_16x16x32_bf16(aa[1][3], bw3, po[1][nt], 0, 0, 0);
            __builtin_amdgcn_s_setprio(0);
        }
        float* ob = out + (size_t)b * (BS * 128);
        #pragma unroll
        for (int nt = 0; nt < 2; ++nt) {
            const int col = 32 * w + 16 * nt + c16;
            const float pbv = proj_b[col];
            #pragma unroll
            for (int mt = 0; mt < 2; ++mt)
                #pragma unroll
                for (int r = 0; r < 4; ++r)
                    ob[(size_t)(16 * mt + 4 * g16 + r) * 128 + col] = po[mt][nt][r] + pbv;
        }
    }
}

extern "C" void kernel_launch(void* const* d_in, const int* in_sizes, int n_in,
                              void* d_out, int out_size, void* d_ws, size_t ws_size,
                              hipStream_t stream) {
    const float* x      = (const float*)d_in[0];
    const int*   ei     = (const int*)d_in[1];
    const float* ev     = (const float*)d_in[2];
    // d_in[3] = positions: unused by the reference output
    const float* qkv_w  = (const float*)d_in[4];
    const float* qkv_b  = (const float*)d_in[5];
    const float* proj_w = (const float*)d_in[6];
    const float* proj_b = (const float*)d_in[7];
    const float* gate_w = (const float*)d_in[8];
    const float* gate_b = (const float*)d_in[9];
    float* out = (float*)d_out;

    const int E  = in_sizes[2];
    const int N  = in_sizes[0] / 128;
    const int nb = N / BS;

    ull* tbl = (ull*)d_ws;
    size_t twords = (size_t)nb * BS * NBC;              // ull count
    size_t tbytes = (twords * sizeof(ull) + 255) & ~(size_t)255;
    unsigned short* wqp = (unsigned short*)((char*)d_ws + tbytes);
    unsigned short* wpp = wqp + 96 * 512;

    zero_prepack_kernel<<<ZB + 256, 256, 0, stream>>>((uint4*)tbl,
                                                      (int)(twords * sizeof(ull) / 16),
                                                      qkv_w, proj_w, wqp, wpp);
    edge_scatter_kernel<<<((E + 3) / 4 + 255) / 256, 256, 0, stream>>>(ei, ei + E, ev, tbl, E);
    block_attn_kernel<<<nb, 256, 0, stream>>>(x, tbl, wqp, wpp, qkv_b, proj_b,
                                              gate_w, gate_b, out);
}

// Round 8
// 261.647 us; speedup vs baseline: 1.1794x; 1.1794x over previous
//
#include <hip/hip_runtime.h>
#include <hip/hip_bf16.h>

#define BS 32
#define NBC 33

typedef unsigned long long ull;
typedef __attribute__((ext_vector_type(8))) __bf16 bf16x8;
typedef __attribute__((ext_vector_type(4))) float f32x4;
typedef __attribute__((ext_vector_type(4))) unsigned short us4;

__device__ __forceinline__ unsigned short f2b(float f) {
    __hip_bfloat16 h = __float2bfloat16(f);
    return *reinterpret_cast<unsigned short*>(&h);
}
__device__ __forceinline__ float b2f(unsigned short u) {
    union { unsigned int i; float f; } x; x.i = ((unsigned int)u) << 16; return x.f;
}
#define LD8(p) (*reinterpret_cast<const bf16x8*>(p))

// ---- fused: zero the ull table (blocks 0..ZB-1) + repack weights (blocks ZB..) ----
#define ZB 2048
__global__ void zero_prepack_kernel(uint4* __restrict__ tbl4, int n4,
                                    const float* __restrict__ qkv_w,
                                    const float* __restrict__ proj_w,
                                    unsigned short* __restrict__ wq,
                                    unsigned short* __restrict__ wp) {
    if (blockIdx.x < ZB) {
        int stride = ZB * 256;
        for (int i = blockIdx.x * 256 + threadIdx.x; i < n4; i += stride)
            tbl4[i] = make_uint4(0u, 0u, 0u, 0u);
    } else {
        int tid = (blockIdx.x - ZB) * 256 + threadIdx.x;   // 0..65535
        int f = tid >> 9, lane = (tid >> 3) & 63, j = tid & 7;
        int ks = f & 3;
        int kk = ks * 32 + (lane >> 4) * 8 + j;
        int nn = lane & 15;
        if (f < 96) {
            int t = f >> 2;                 // 0..23
            int w = t / 6, s = t % 6;
            int g = (s < 2) ? (2 * w + s) : (s < 4) ? (8 + 2 * w + (s - 2)) : (16 + 2 * w + (s - 4));
            wq[tid] = f2b(qkv_w[kk * 384 + g * 16 + nn]);
        } else {
            int f2 = f - 96;                // proj frag = nt_global*4+ks
            wp[f2 * 512 + lane * 8 + j] = f2b(proj_w[kk * 128 + (f2 >> 2) * 16 + nn]);
        }
    }
}

// ---- pass 1: last-edge-wins scatter; key = (edge_id+1)<<32 | float_bits(value) ----
__global__ void edge_scatter_kernel(const int* __restrict__ rows,
                                    const int* __restrict__ cols,
                                    const float* __restrict__ vals,
                                    ull* __restrict__ tbl, int E) {
    int base = (blockIdx.x * 256 + threadIdx.x) * 4;
    if (base >= E) return;
    if (base + 4 <= E) {
        int4 r4 = *reinterpret_cast<const int4*>(rows + base);
        int4 c4 = *reinterpret_cast<const int4*>(cols + base);
        float4 v4 = *reinterpret_cast<const float4*>(vals + base);
        int rr[4] = {r4.x, r4.y, r4.z, r4.w};
        int cc[4] = {c4.x, c4.y, c4.z, c4.w};
        float vv[4] = {v4.x, v4.y, v4.z, v4.w};
        #pragma unroll
        for (int k = 0; k < 4; ++k) {
            int r = rr[k], c = cc[k];
            if ((r >> 5) == (c >> 5) && r != c) {
                ull key = ((ull)(unsigned)(base + k + 1) << 32) | (ull)__float_as_uint(vv[k]);
                atomicMax(&tbl[((size_t)(r >> 5) * BS + (r & 31)) * NBC + (c & 31)], key);
            }
        }
    } else {
        for (int e = base; e < E && e < base + 4; ++e) {
            int r = rows[e], c = cols[e];
            if ((r >> 5) == (c >> 5) && r != c) {
                ull key = ((ull)(unsigned)(e + 1) << 32) | (ull)__float_as_uint(vals[e]);
                atomicMax(&tbl[((size_t)(r >> 5) * BS + (r & 31)) * NBC + (c & 31)], key);
            }
        }
    }
}

// ---- main fused kernel: one 4-wave WG per block; wave w owns head w end-to-end ----
// Barriers ONLY at cross-wave flows: x-staging, xs-overlay release, attn-out->proj.
// All QKV/QK^T/softmax/PV LDS traffic is wave-private (qs[w]/ksm[w]/vT[w]).
__global__ __launch_bounds__(256)
void block_attn_kernel(const float* __restrict__ x,
                       const ull* __restrict__ tbl,
                       const unsigned short* __restrict__ wq,
                       const unsigned short* __restrict__ wp,
                       const float* __restrict__ qkv_b,
                       const float* __restrict__ proj_b,
                       const float* __restrict__ gate_w,
                       const float* __restrict__ gate_b,
                       float* __restrict__ out) {
    __shared__ __align__(16) unsigned char smem[31040];
    unsigned short (*qs)[32][40]  = (unsigned short (*)[32][40])(smem);           // 10240 B: Q -> P -> attn-out
    unsigned short (*ksm)[33][40] = (unsigned short (*)[33][40])(smem + 10240);   // 10560 B: K rows 0-31 + mean(32)
    unsigned short (*vT)[32][40]  = (unsigned short (*)[32][40])(smem + 20800);   // 10240 B: V^T; col32=mean, col33=pcol
    unsigned short (*xs)[136]     = (unsigned short (*)[136])(smem + 20800);      //  8704 B overlay (x staging)

    const int b = blockIdx.x, t = threadIdx.x;
    const int w = t >> 6, l = t & 63, g16 = l >> 4, c16 = l & 15;
    const f32x4 z4 = {0.f, 0.f, 0.f, 0.f};
    const float NEG = -1.0e30f;

    // ---- phase 0: stage x block (coalesced float4 -> bf16 LDS) ----
    const float* xb = x + (size_t)b * (BS * 128);
    #pragma unroll
    for (int it = 0; it < 4; ++it) {
        int idx = (t + it * 256) * 4;
        float4 v = *reinterpret_cast<const float4*>(xb + idx);
        us4 u; u.x = f2b(v.x); u.y = f2b(v.y); u.z = f2b(v.z); u.w = f2b(v.w);
        *reinterpret_cast<us4*>(&xs[idx >> 7][idx & 127]) = u;
    }

    // ---- edge bias wb per score slot from packed table (value embedded) ----
    float wb[2][4][3];
    {
        const ull* tb = tbl + (size_t)b * (BS * NBC);
        #pragma unroll
        for (int mt = 0; mt < 2; ++mt)
            #pragma unroll
            for (int r = 0; r < 4; ++r) {
                const int i = 16 * mt + 4 * g16 + r;
                #pragma unroll
                for (int nt = 0; nt < 2; ++nt) {
                    const int j = 16 * nt + c16;
                    const ull wv = tb[i * NBC + j];
                    wb[mt][r][nt] = (j == i) ? 1.f
                                   : (wv ? __uint_as_float((unsigned)(wv & 0xffffffffu)) : NEG);
                }
                wb[mt][r][2] = (c16 == 0) ? 1.f : NEG;
            }
    }
    __syncthreads();   // x staged

    // ---- A-fragments from LDS ----
    bf16x8 a[2][4];
    #pragma unroll
    for (int mt = 0; mt < 2; ++mt)
        #pragma unroll
        for (int ks = 0; ks < 4; ++ks)
            a[mt][ks] = LD8(&xs[c16 + 16 * mt][ks * 32 + g16 * 8]);
    __syncthreads();   // xs consumed; overlay region may now be written as vT

    // ---- QKV for head w: 6 n-tiles (q0,q1,k0,k1,v0,v1), K=128 ----
    {
        const unsigned short* wqs = wq + (size_t)(w * 24) * 512 + l * 8;
        #pragma unroll
        for (int s = 0; s < 6; ++s) {
            bf16x8 bn[4];
            #pragma unroll
            for (int ks = 0; ks < 4; ++ks) bn[ks] = LD8(wqs + (s * 4 + ks) * 512);
            f32x4 acc0 = z4, acc1 = z4;
            __builtin_amdgcn_s_setprio(1);
            #pragma unroll
            for (int ks = 0; ks < 4; ++ks) {
                acc0 = __builtin_amdgcn_mfma_f32_16x16x32_bf16(a[0][ks], bn[ks], acc0, 0, 0, 0);
                acc1 = __builtin_amdgcn_mfma_f32_16x16x32_bf16(a[1][ks], bn[ks], acc1, 0, 0, 0);
            }
            __builtin_amdgcn_s_setprio(0);
            const float bias = qkv_b[(s >> 1) * 128 + 32 * w + 16 * (s & 1) + c16];
            const int cc = 16 * (s & 1) + c16;
            if (s < 2) {
                #pragma unroll
                for (int r = 0; r < 4; ++r) {
                    qs[w][4 * g16 + r][cc]      = f2b(acc0[r] + bias);
                    qs[w][16 + 4 * g16 + r][cc] = f2b(acc1[r] + bias);
                }
            } else {
                float csum = acc0[0] + acc0[1] + acc0[2] + acc0[3]
                           + acc1[0] + acc1[1] + acc1[2] + acc1[3];
                csum += __shfl_xor(csum, 16, 64);
                csum += __shfl_xor(csum, 32, 64);
                const float meanv = csum * (1.f / 32.f) + bias;
                if (s < 4) {
                    #pragma unroll
                    for (int r = 0; r < 4; ++r) {
                        ksm[w][4 * g16 + r][cc]      = f2b(acc0[r] + bias);
                        ksm[w][16 + 4 * g16 + r][cc] = f2b(acc1[r] + bias);
                    }
                    if (g16 == 0) ksm[w][32][cc] = f2b(meanv);
                } else {
                    #pragma unroll
                    for (int r = 0; r < 4; ++r) {
                        vT[w][cc][4 * g16 + r]      = f2b(acc0[r] + bias);
                        vT[w][cc][16 + 4 * g16 + r] = f2b(acc1[r] + bias);
                    }
                    if (g16 == 0) vT[w][cc][32] = f2b(meanv);
                }
            }
        }
    }
    // (no barrier: qs/ksm/vT wave-private; same-wave ds ordering via lgkmcnt)

    // ---- QK^T (K=32); mean-row fragment masked to lanes c16==0 via select ----
    f32x4 s[2][3];
    {
        bf16x8 aq0 = LD8(&qs[w][c16][g16 * 8]);
        bf16x8 aq1 = LD8(&qs[w][16 + c16][g16 * 8]);
        bf16x8 bk0 = LD8(&ksm[w][c16][g16 * 8]);
        bf16x8 bk1 = LD8(&ksm[w][16 + c16][g16 * 8]);
        bf16x8 bk2 = LD8(&ksm[w][32][g16 * 8]);      // mean row, broadcast
        bf16x8 zb;
        #pragma unroll
        for (int q = 0; q < 8; ++q) zb[q] = (__bf16)0.f;
        if (c16 != 0) bk2 = zb;                       // only col 32 of tile 2 is real
        __builtin_amdgcn_s_setprio(1);
        s[0][0] = __builtin_amdgcn_mfma_f32_16x16x32_bf16(aq0, bk0, z4, 0, 0, 0);
        s[0][1] = __builtin_amdgcn_mfma_f32_16x16x32_bf16(aq0, bk1, z4, 0, 0, 0);
        s[0][2] = __builtin_amdgcn_mfma_f32_16x16x32_bf16(aq0, bk2, z4, 0, 0, 0);
        s[1][0] = __builtin_amdgcn_mfma_f32_16x16x32_bf16(aq1, bk0, z4, 0, 0, 0);
        s[1][1] = __builtin_amdgcn_mfma_f32_16x16x32_bf16(aq1, bk1, z4, 0, 0, 0);
        s[1][2] = __builtin_amdgcn_mfma_f32_16x16x32_bf16(aq1, bk2, z4, 0, 0, 0);
        __builtin_amdgcn_s_setprio(0);
    }

    // ---- softmax with max-subtraction + gate; stage P (combined) ----
    {
        const float scale = 0.17677669529663687f;   // 32^-0.5
        const float gwh = gate_w[w], gbh = gate_b[w];
        #pragma unroll
        for (int mt = 0; mt < 2; ++mt)
            #pragma unroll
            for (int r = 0; r < 4; ++r) {
                const int i = 16 * mt + 4 * g16 + r;
                float sc[3];
                #pragma unroll
                for (int k = 0; k < 3; ++k) sc[k] = s[mt][k][r] * scale + wb[mt][r][k];
                float mx = fmaxf(fmaxf(sc[0], sc[1]), sc[2]);
                mx = fmaxf(mx, __shfl_xor(mx, 1, 64));
                mx = fmaxf(mx, __shfl_xor(mx, 2, 64));
                mx = fmaxf(mx, __shfl_xor(mx, 4, 64));
                mx = fmaxf(mx, __shfl_xor(mx, 8, 64));
                float e0 = __expf(sc[0] - mx), e1 = __expf(sc[1] - mx), e2 = __expf(sc[2] - mx);
                float sum = e0 + e1 + e2;
                sum += __shfl_xor(sum, 1, 64);
                sum += __shfl_xor(sum, 2, 64);
                sum += __shfl_xor(sum, 4, 64);
                sum += __shfl_xor(sum, 8, 64);
                const float inv = __builtin_amdgcn_rcpf(sum);
                float gt0 = (wb[mt][r][0] > -1.0e29f) ? wb[mt][r][0] * gwh + gbh : 0.f;
                float gt1 = (wb[mt][r][1] > -1.0e29f) ? wb[mt][r][1] * gwh + gbh : 0.f;
                float gt2 = (wb[mt][r][2] > -1.0e29f) ? gwh + gbh : 0.f;
                qs[w][i][c16]      = f2b(e0 * inv + gt0);
                qs[w][i][16 + c16] = f2b(e1 * inv + gt1);
                if (c16 == 0) vT[w][i][33] = f2b(e2 * inv + gt2);   // pcol
            }
    }
    // (no barrier: P/pcol wave-private)

    // ---- PV (rows 0-31 via MFMA, block-node row via rank-1) -> attn-out into qs ----
    {
        bf16x8 ap0 = LD8(&qs[w][c16][g16 * 8]);
        bf16x8 ap1 = LD8(&qs[w][16 + c16][g16 * 8]);
        f32x4 o[2][2];
        __builtin_amdgcn_s_setprio(1);
        #pragma unroll
        for (int nt = 0; nt < 2; ++nt) {
            bf16x8 bv = LD8(&vT[w][16 * nt + c16][g16 * 8]);
            o[0][nt] = __builtin_amdgcn_mfma_f32_16x16x32_bf16(ap0, bv, z4, 0, 0, 0);
            o[1][nt] = __builtin_amdgcn_mfma_f32_16x16x32_bf16(ap1, bv, z4, 0, 0, 0);
        }
        __builtin_amdgcn_s_setprio(0);
        #pragma unroll
        for (int nt = 0; nt < 2; ++nt) {
            const float vm = b2f(vT[w][16 * nt + c16][32]);
            #pragma unroll
            for (int mt = 0; mt < 2; ++mt)
                #pragma unroll
                for (int r = 0; r < 4; ++r)
                    o[mt][nt][r] += b2f(vT[w][16 * mt + 4 * g16 + r][33]) * vm;
        }
        #pragma unroll
        for (int mt = 0; mt < 2; ++mt)
            #pragma unroll
            for (int nt = 0; nt < 2; ++nt)
                #pragma unroll
                for (int r = 0; r < 4; ++r)
                    qs[w][16 * mt + 4 * g16 + r][16 * nt + c16] = f2b(o[mt][nt][r]);
    }
    __syncthreads();   // all heads' attn-out ready (cross-wave)

    // ---- projection: k-step h reads head-h buffer; wave w owns out cols [32w,32w+32) ----
    {
        bf16x8 aa[2][4];
        #pragma unroll
        for (int mt = 0; mt < 2; ++mt)
            #pragma unroll
            for (int h = 0; h < 4; ++h)
                aa[mt][h] = LD8(&qs[h][c16 + 16 * mt][g16 * 8]);
        f32x4 po[2][2];
        po[0][0] = z4; po[0][1] = z4; po[1][0] = z4; po[1][1] = z4;
        const unsigned short* wps = wp + l * 8;
        #pragma unroll
        for (int nt = 0; nt < 2; ++nt) {
            bf16x8 bw0 = LD8(wps + (size_t)((2 * w + nt) * 4 + 0) * 512);
            bf16x8 bw1 = LD8(wps + (size_t)((2 * w + nt) * 4 + 1) * 512);
            bf16x8 bw2 = LD8(wps + (size_t)((2 * w + nt) * 4 + 2) * 512);
            bf16x8 bw3 = LD8(wps + (size_t)((2 * w + nt) * 4 + 3) * 512);
            __builtin_amdgcn_s_setprio(1);
            po[0][nt] = __builtin_amdgcn_mfma_f32_16x16x32_bf16(aa[0][0], bw0, po[0][nt], 0, 0, 0);
            po[1][nt] = __builtin_amdgcn_mfma_f32_16x16x32_bf16(aa[1][0], bw0, po[1][nt], 0, 0, 0);
            po[0][nt] = __builtin_amdgcn_mfma_f32_16x16x32_bf16(aa[0][1], bw1, po[0][nt], 0, 0, 0);
            po[1][nt] = __builtin_amdgcn_mfma_f32_16x16x32_bf16(aa[1][1], bw1, po[1][nt], 0, 0, 0);
            po[0][nt] = __builtin_amdgcn_mfma_f32_16x16x32_bf16(aa[0][2], bw2, po[0][nt], 0, 0, 0);
            po[1][nt] = __builtin_amdgcn_mfma_f32_16x16x32_bf16(aa[1][2], bw2, po[1][nt], 0, 0, 0);
            po[0][nt] = __builtin_amdgcn_mfma_f32_16x16x32_bf16(aa[0][3], bw3, po[0][nt], 0, 0, 0);
            po[1][nt] = __builtin_amdgcn_mfma_f32_16x16x32_bf16(aa[1][3], bw3, po[1][nt], 0, 0, 0);
            __builtin_amdgcn_s_setprio(0);
        }
        float* ob = out + (size_t)b * (BS * 128);
        #pragma unroll
        for (int nt = 0; nt < 2; ++nt) {
            const int col = 32 * w + 16 * nt + c16;
            const float pbv = proj_b[col];
            #pragma unroll
            for (int mt = 0; mt < 2; ++mt)
                #pragma unroll
                for (int r = 0; r < 4; ++r)
                    ob[(size_t)(16 * mt + 4 * g16 + r) * 128 + col] = po[mt][nt][r] + pbv;
        }
    }
}

extern "C" void kernel_launch(void* const* d_in, const int* in_sizes, int n_in,
                              void* d_out, int out_size, void* d_ws, size_t ws_size,
                              hipStream_t stream) {
    const float* x      = (const float*)d_in[0];
    const int*   ei     = (const int*)d_in[1];
    const float* ev     = (const float*)d_in[2];
    // d_in[3] = positions: unused by the reference output
    const float* qkv_w  = (const float*)d_in[4];
    const float* qkv_b  = (const float*)d_in[5];
    const float* proj_w = (const float*)d_in[6];
    const float* proj_b = (const float*)d_in[7];
    const float* gate_w = (const float*)d_in[8];
    const float* gate_b = (const float*)d_in[9];
    float* out = (float*)d_out;

    const int E  = in_sizes[2];
    const int N  = in_sizes[0] / 128;
    const int nb = N / BS;

    ull* tbl = (ull*)d_ws;
    size_t twords = (size_t)nb * BS * NBC;              // ull count
    size_t tbytes = (twords * sizeof(ull) + 255) & ~(size_t)255;
    unsigned short* wqp = (unsigned short*)((char*)d_ws + tbytes);
    unsigned short* wpp = wqp + 96 * 512;

    zero_prepack_kernel<<<ZB + 256, 256, 0, stream>>>((uint4*)tbl,
                                                      (int)(twords * sizeof(ull) / 16),
                                                      qkv_w, proj_w, wqp, wpp);
    edge_scatter_kernel<<<((E + 3) / 4 + 255) / 256, 256, 0, stream>>>(ei, ei + E, ev, tbl, E);
    block_attn_kernel<<<nb, 256, 0, stream>>>(x, tbl, wqp, wpp, qkv_b, proj_b,
                                              gate_w, gate_b, out);
}

// Round 9
// 261.316 us; speedup vs baseline: 1.1809x; 1.0013x over previous
//
#include <hip/hip_runtime.h>
#include <hip/hip_bf16.h>

#define BS 32
#define NBC 33

typedef unsigned long long ull;
typedef __attribute__((ext_vector_type(8))) __bf16 bf16x8;
typedef __attribute__((ext_vector_type(4))) float f32x4;
typedef __attribute__((ext_vector_type(4))) unsigned short us4;

__device__ __forceinline__ unsigned short f2b(float f) {
    __hip_bfloat16 h = __float2bfloat16(f);
    return *reinterpret_cast<unsigned short*>(&h);
}
__device__ __forceinline__ float b2f(unsigned short u) {
    union { unsigned int i; float f; } x; x.i = ((unsigned int)u) << 16; return x.f;
}
#define LD8(p) (*reinterpret_cast<const bf16x8*>(p))

// ---- fused: zero the ull table (blocks 0..ZB-1) + repack weights (blocks ZB..) ----
#define ZB 2048
__global__ void zero_prepack_kernel(uint4* __restrict__ tbl4, int n4,
                                    const float* __restrict__ qkv_w,
                                    const float* __restrict__ proj_w,
                                    unsigned short* __restrict__ wq,
                                    unsigned short* __restrict__ wp) {
    if (blockIdx.x < ZB) {
        int stride = ZB * 256;
        for (int i = blockIdx.x * 256 + threadIdx.x; i < n4; i += stride)
            tbl4[i] = make_uint4(0u, 0u, 0u, 0u);
    } else {
        int tid = (blockIdx.x - ZB) * 256 + threadIdx.x;   // 0..65535
        int f = tid >> 9, lane = (tid >> 3) & 63, j = tid & 7;
        int ks = f & 3;
        int kk = ks * 32 + (lane >> 4) * 8 + j;
        int nn = lane & 15;
        if (f < 96) {
            int t = f >> 2;                 // 0..23
            int w = t / 6, s = t % 6;
            int g = (s < 2) ? (2 * w + s) : (s < 4) ? (8 + 2 * w + (s - 2)) : (16 + 2 * w + (s - 4));
            wq[tid] = f2b(qkv_w[kk * 384 + g * 16 + nn]);
        } else {
            int f2 = f - 96;                // proj frag = nt_global*4+ks
            wp[f2 * 512 + lane * 8 + j] = f2b(proj_w[kk * 128 + (f2 >> 2) * 16 + nn]);
        }
    }
}

// ---- pass 1: last-edge-wins scatter; key = (edge_id+1)<<32 | float_bits(value) ----
__global__ void edge_scatter_kernel(const int* __restrict__ rows,
                                    const int* __restrict__ cols,
                                    const float* __restrict__ vals,
                                    ull* __restrict__ tbl, int E) {
    int base = (blockIdx.x * 256 + threadIdx.x) * 4;
    if (base >= E) return;
    if (base + 4 <= E) {
        int4 r4 = *reinterpret_cast<const int4*>(rows + base);
        int4 c4 = *reinterpret_cast<const int4*>(cols + base);
        float4 v4 = *reinterpret_cast<const float4*>(vals + base);
        int rr[4] = {r4.x, r4.y, r4.z, r4.w};
        int cc[4] = {c4.x, c4.y, c4.z, c4.w};
        float vv[4] = {v4.x, v4.y, v4.z, v4.w};
        #pragma unroll
        for (int k = 0; k < 4; ++k) {
            int r = rr[k], c = cc[k];
            if ((r >> 5) == (c >> 5) && r != c) {
                ull key = ((ull)(unsigned)(base + k + 1) << 32) | (ull)__float_as_uint(vv[k]);
                atomicMax(&tbl[((size_t)(r >> 5) * BS + (r & 31)) * NBC + (c & 31)], key);
            }
        }
    } else {
        for (int e = base; e < E && e < base + 4; ++e) {
            int r = rows[e], c = cols[e];
            if ((r >> 5) == (c >> 5) && r != c) {
                ull key = ((ull)(unsigned)(e + 1) << 32) | (ull)__float_as_uint(vals[e]);
                atomicMax(&tbl[((size_t)(r >> 5) * BS + (r & 31)) * NBC + (c & 31)], key);
            }
        }
    }
}

// ---- main fused kernel: one 8-wave WG (512 thr) per block ----
// Head h = (t>>6)&3 gets a wave PAIR; half = t>>8 splits work:
//   QKV by n-tiles (s = {half, half+2, half+4}) -> half the weight loads/wave;
//   QK^T/softmax/PV/store by output-row half (rows 16*half..+15).
// All staging writes are column- or row-disjoint between halves (race-free).
__global__ __launch_bounds__(512)
void block_attn_kernel(const float* __restrict__ x,
                       const ull* __restrict__ tbl,
                       const unsigned short* __restrict__ wq,
                       const unsigned short* __restrict__ wp,
                       const float* __restrict__ qkv_b,
                       const float* __restrict__ proj_b,
                       const float* __restrict__ gate_w,
                       const float* __restrict__ gate_b,
                       float* __restrict__ out) {
    __shared__ __align__(16) unsigned char smem[31040];
    unsigned short (*qs)[32][40]  = (unsigned short (*)[32][40])(smem);           // Q -> P -> attn-out
    unsigned short (*ksm)[33][40] = (unsigned short (*)[33][40])(smem + 10240);   // K rows + mean(32)
    unsigned short (*vT)[32][40]  = (unsigned short (*)[32][40])(smem + 20800);   // V^T; col32=mean, col33=pcol
    unsigned short (*xs)[136]     = (unsigned short (*)[136])(smem + 20800);      // overlay (x staging)

    const int b = blockIdx.x, t = threadIdx.x;
    const int h = (t >> 6) & 3, half = t >> 8;
    const int l = t & 63, g16 = l >> 4, c16 = l & 15;
    const f32x4 z4 = {0.f, 0.f, 0.f, 0.f};
    const float NEG = -1.0e30f;

    // ---- phase 0: stage x block (coalesced float4 -> bf16 LDS), 512 threads ----
    const float* xb = x + (size_t)b * (BS * 128);
    #pragma unroll
    for (int it = 0; it < 2; ++it) {
        int idx = (t + it * 512) * 4;
        float4 v = *reinterpret_cast<const float4*>(xb + idx);
        us4 u; u.x = f2b(v.x); u.y = f2b(v.y); u.z = f2b(v.z); u.w = f2b(v.w);
        *reinterpret_cast<us4*>(&xs[idx >> 7][idx & 127]) = u;
    }

    // ---- edge bias wb for own-half rows i = 16*half + 4*g16 + r ----
    float wb[4][3];
    {
        const ull* tb = tbl + (size_t)b * (BS * NBC);
        #pragma unroll
        for (int r = 0; r < 4; ++r) {
            const int i = 16 * half + 4 * g16 + r;
            #pragma unroll
            for (int nt = 0; nt < 2; ++nt) {
                const int j = 16 * nt + c16;
                const ull wv = tb[i * NBC + j];
                wb[r][nt] = (j == i) ? 1.f
                           : (wv ? __uint_as_float((unsigned)(wv & 0xffffffffu)) : NEG);
            }
            wb[r][2] = (c16 == 0) ? 1.f : NEG;
        }
    }
    __syncthreads();   // x staged

    // ---- A-fragments (all 32 rows) from LDS ----
    bf16x8 a[2][4];
    #pragma unroll
    for (int mt = 0; mt < 2; ++mt)
        #pragma unroll
        for (int ks = 0; ks < 4; ++ks)
            a[mt][ks] = LD8(&xs[c16 + 16 * mt][ks * 32 + g16 * 8]);
    __syncthreads();   // xs consumed; overlay region may now be written as vT

    // ---- QKV: this half's 3 n-tiles (q,k,v cols [16*half,16*half+16) of head h) ----
    {
        const unsigned short* wqs = wq + (size_t)(h * 24) * 512 + l * 8;
        #pragma unroll
        for (int si = 0; si < 3; ++si) {
            const int s = 2 * si + half;
            bf16x8 bn[4];
            #pragma unroll
            for (int ks = 0; ks < 4; ++ks) bn[ks] = LD8(wqs + (s * 4 + ks) * 512);
            f32x4 acc0 = z4, acc1 = z4;
            __builtin_amdgcn_s_setprio(1);
            #pragma unroll
            for (int ks = 0; ks < 4; ++ks) {
                acc0 = __builtin_amdgcn_mfma_f32_16x16x32_bf16(a[0][ks], bn[ks], acc0, 0, 0, 0);
                acc1 = __builtin_amdgcn_mfma_f32_16x16x32_bf16(a[1][ks], bn[ks], acc1, 0, 0, 0);
            }
            __builtin_amdgcn_s_setprio(0);
            const float bias = qkv_b[si * 128 + 32 * h + 16 * half + c16];
            const int cc = 16 * half + c16;
            if (si == 0) {
                #pragma unroll
                for (int r = 0; r < 4; ++r) {
                    qs[h][4 * g16 + r][cc]      = f2b(acc0[r] + bias);
                    qs[h][16 + 4 * g16 + r][cc] = f2b(acc1[r] + bias);
                }
            } else {
                float csum = acc0[0] + acc0[1] + acc0[2] + acc0[3]
                           + acc1[0] + acc1[1] + acc1[2] + acc1[3];
                csum += __shfl_xor(csum, 16, 64);
                csum += __shfl_xor(csum, 32, 64);
                const float meanv = csum * (1.f / 32.f) + bias;
                if (si == 1) {
                    #pragma unroll
                    for (int r = 0; r < 4; ++r) {
                        ksm[h][4 * g16 + r][cc]      = f2b(acc0[r] + bias);
                        ksm[h][16 + 4 * g16 + r][cc] = f2b(acc1[r] + bias);
                    }
                    if (g16 == 0) ksm[h][32][cc] = f2b(meanv);
                } else {
                    #pragma unroll
                    for (int r = 0; r < 4; ++r) {
                        vT[h][cc][4 * g16 + r]      = f2b(acc0[r] + bias);
                        vT[h][cc][16 + 4 * g16 + r] = f2b(acc1[r] + bias);
                    }
                    if (g16 == 0) vT[h][cc][32] = f2b(meanv);
                }
            }
        }
    }
    __syncthreads();   // QKV staged (consumers read across halves)

    // ---- QK^T for own-half rows (M=16) ----
    f32x4 sS[3];
    {
        bf16x8 aq  = LD8(&qs[h][16 * half + c16][g16 * 8]);
        bf16x8 bk0 = LD8(&ksm[h][c16][g16 * 8]);
        bf16x8 bk1 = LD8(&ksm[h][16 + c16][g16 * 8]);
        bf16x8 bk2 = LD8(&ksm[h][32][g16 * 8]);      // mean row, broadcast
        bf16x8 zb;
        #pragma unroll
        for (int q = 0; q < 8; ++q) zb[q] = (__bf16)0.f;
        if (c16 != 0) bk2 = zb;                       // only col 32 of tile 2 is real
        __builtin_amdgcn_s_setprio(1);
        sS[0] = __builtin_amdgcn_mfma_f32_16x16x32_bf16(aq, bk0, z4, 0, 0, 0);
        sS[1] = __builtin_amdgcn_mfma_f32_16x16x32_bf16(aq, bk1, z4, 0, 0, 0);
        sS[2] = __builtin_amdgcn_mfma_f32_16x16x32_bf16(aq, bk2, z4, 0, 0, 0);
        __builtin_amdgcn_s_setprio(0);
    }

    // ---- softmax (max-sub, overflow-proof) + gate; stage P (own-half rows) ----
    {
        const float scale = 0.17677669529663687f;   // 32^-0.5
        const float gwh = gate_w[h], gbh = gate_b[h];
        #pragma unroll
        for (int r = 0; r < 4; ++r) {
            const int i = 16 * half + 4 * g16 + r;
            float sc[3];
            #pragma unroll
            for (int k = 0; k < 3; ++k) sc[k] = sS[k][r] * scale + wb[r][k];
            float mx = fmaxf(fmaxf(sc[0], sc[1]), sc[2]);
            mx = fmaxf(mx, __shfl_xor(mx, 1, 64));
            mx = fmaxf(mx, __shfl_xor(mx, 2, 64));
            mx = fmaxf(mx, __shfl_xor(mx, 4, 64));
            mx = fmaxf(mx, __shfl_xor(mx, 8, 64));
            float e0 = __expf(sc[0] - mx), e1 = __expf(sc[1] - mx), e2 = __expf(sc[2] - mx);
            float sum = e0 + e1 + e2;
            sum += __shfl_xor(sum, 1, 64);
            sum += __shfl_xor(sum, 2, 64);
            sum += __shfl_xor(sum, 4, 64);
            sum += __shfl_xor(sum, 8, 64);
            const float inv = __builtin_amdgcn_rcpf(sum);
            float gt0 = (wb[r][0] > -1.0e29f) ? wb[r][0] * gwh + gbh : 0.f;
            float gt1 = (wb[r][1] > -1.0e29f) ? wb[r][1] * gwh + gbh : 0.f;
            float gt2 = (wb[r][2] > -1.0e29f) ? gwh + gbh : 0.f;
            qs[h][i][c16]      = f2b(e0 * inv + gt0);
            qs[h][i][16 + c16] = f2b(e1 * inv + gt1);
            if (c16 == 0) vT[h][i][33] = f2b(e2 * inv + gt2);   // pcol
        }
    }
    // (no barrier: P rows and pcol are wave-local; V/mean staged before barrier above)

    // ---- PV for own-half rows -> attn-out into qs ----
    {
        bf16x8 ap = LD8(&qs[h][16 * half + c16][g16 * 8]);
        f32x4 o[2];
        __builtin_amdgcn_s_setprio(1);
        #pragma unroll
        for (int nt = 0; nt < 2; ++nt) {
            bf16x8 bv = LD8(&vT[h][16 * nt + c16][g16 * 8]);
            o[nt] = __builtin_amdgcn_mfma_f32_16x16x32_bf16(ap, bv, z4, 0, 0, 0);
        }
        __builtin_amdgcn_s_setprio(0);
        #pragma unroll
        for (int nt = 0; nt < 2; ++nt) {
            const float vm = b2f(vT[h][16 * nt + c16][32]);
            #pragma unroll
            for (int r = 0; r < 4; ++r)
                o[nt][r] += b2f(vT[h][16 * half + 4 * g16 + r][33]) * vm;
        }
        #pragma unroll
        for (int nt = 0; nt < 2; ++nt)
            #pragma unroll
            for (int r = 0; r < 4; ++r)
                qs[h][16 * half + 4 * g16 + r][16 * nt + c16] = f2b(o[nt][r]);
    }
    __syncthreads();   // all heads' attn-out ready (cross-wave)

    // ---- projection: 8 waves; wave ct = t>>6 owns out cols [16ct, 16ct+16) ----
    {
        const int ct = t >> 6;
        bf16x8 aa[2][4];
        #pragma unroll
        for (int mt = 0; mt < 2; ++mt)
            #pragma unroll
            for (int hh = 0; hh < 4; ++hh)
                aa[mt][hh] = LD8(&qs[hh][c16 + 16 * mt][g16 * 8]);
        f32x4 po[2];
        po[0] = z4; po[1] = z4;
        const unsigned short* wps = wp + l * 8;
        bf16x8 bw0 = LD8(wps + (size_t)(ct * 4 + 0) * 512);
        bf16x8 bw1 = LD8(wps + (size_t)(ct * 4 + 1) * 512);
        bf16x8 bw2 = LD8(wps + (size_t)(ct * 4 + 2) * 512);
        bf16x8 bw3 = LD8(wps + (size_t)(ct * 4 + 3) * 512);
        __builtin_amdgcn_s_setprio(1);
        po[0] = __builtin_amdgcn_mfma_f32_16x16x32_bf16(aa[0][0], bw0, po[0], 0, 0, 0);
        po[1] = __builtin_amdgcn_mfma_f32_16x16x32_bf16(aa[1][0], bw0, po[1], 0, 0, 0);
        po[0] = __builtin_amdgcn_mfma_f32_16x16x32_bf16(aa[0][1], bw1, po[0], 0, 0, 0);
        po[1] = __builtin_amdgcn_mfma_f32_16x16x32_bf16(aa[1][1], bw1, po[1], 0, 0, 0);
        po[0] = __builtin_amdgcn_mfma_f32_16x16x32_bf16(aa[0][2], bw2, po[0], 0, 0, 0);
        po[1] = __builtin_amdgcn_mfma_f32_16x16x32_bf16(aa[1][2], bw2, po[1], 0, 0, 0);
        po[0] = __builtin_amdgcn_mfma_f32_16x16x32_bf16(aa[0][3], bw3, po[0], 0, 0, 0);
        po[1] = __builtin_amdgcn_mfma_f32_16x16x32_bf16(aa[1][3], bw3, po[1], 0, 0, 0);
        __builtin_amdgcn_s_setprio(0);
        float* ob = out + (size_t)b * (BS * 128);
        const int col = 16 * ct + c16;
        const float pbv = proj_b[col];
        #pragma unroll
        for (int mt = 0; mt < 2; ++mt)
            #pragma unroll
            for (int r = 0; r < 4; ++r)
                ob[(size_t)(16 * mt + 4 * g16 + r) * 128 + col] = po[mt][r] + pbv;
    }
}

extern "C" void kernel_launch(void* const* d_in, const int* in_sizes, int n_in,
                              void* d_out, int out_size, void* d_ws, size_t ws_size,
                              hipStream_t stream) {
    const float* x      = (const float*)d_in[0];
    const int*   ei     = (const int*)d_in[1];
    const float* ev     = (const float*)d_in[2];
    // d_in[3] = positions: unused by the reference output
    const float* qkv_w  = (const float*)d_in[4];
    const float* qkv_b  = (const float*)d_in[5];
    const float* proj_w = (const float*)d_in[6];
    const float* proj_b = (const float*)d_in[7];
    const float* gate_w = (const float*)d_in[8];
    const float* gate_b = (const float*)d_in[9];
    float* out = (float*)d_out;

    const int E  = in_sizes[2];
    const int N  = in_sizes[0] / 128;
    const int nb = N / BS;

    ull* tbl = (ull*)d_ws;
    size_t twords = (size_t)nb * BS * NBC;              // ull count
    size_t tbytes = (twords * sizeof(ull) + 255) & ~(size_t)255;
    unsigned short* wqp = (unsigned short*)((char*)d_ws + tbytes);
    unsigned short* wpp = wqp + 96 * 512;

    zero_prepack_kernel<<<ZB + 256, 256, 0, stream>>>((uint4*)tbl,
                                                      (int)(twords * sizeof(ull) / 16),
                                                      qkv_w, proj_w, wqp, wpp);
    edge_scatter_kernel<<<((E + 3) / 4 + 255) / 256, 256, 0, stream>>>(ei, ei + E, ev, tbl, E);
    block_attn_kernel<<<nb, 512, 0, stream>>>(x, tbl, wqp, wpp, qkv_b, proj_b,
                                              gate_w, gate_b, out);
}